// Round 4
// baseline (236.327 us; speedup 1.0000x reference)
//
#include <hip/hip_runtime.h>
#include <stdint.h>

typedef __attribute__((ext_vector_type(8))) short bhalf8;
typedef __attribute__((ext_vector_type(8))) unsigned short u16x8;
typedef __attribute__((ext_vector_type(4))) float f32x4;

__device__ __forceinline__ unsigned short f2bf(float f) {
  unsigned int u = __float_as_uint(f);
  u += 0x7FFFu + ((u >> 16) & 1u);  // RNE
  return (unsigned short)(u >> 16);
}

__device__ __forceinline__ void gload16(const void* g, void* l) {
  __builtin_amdgcn_global_load_lds(
      (const __attribute__((address_space(1))) void*)g,
      (__attribute__((address_space(3))) void*)l, 16, 0, 0);
}

template <int N>
__device__ __forceinline__ void vwait() {
  if constexpr (N == 0)
    asm volatile("s_waitcnt vmcnt(0)" ::: "memory");
  else if constexpr (N == 8)
    asm volatile("s_waitcnt vmcnt(8)" ::: "memory");
  else if constexpr (N == 12)
    asm volatile("s_waitcnt vmcnt(12)" ::: "memory");
  else
    asm volatile("s_waitcnt vmcnt(16)" ::: "memory");
}

// W (16,256,256,2) fp32 -> bf16 A-tiles: per layer, per kstep [m=256][k'=64],
// element-in-tile = m*64 + (k' ^ ((m&7)<<3))
__global__ void convert_w_kernel(const float* __restrict__ W,
                                 unsigned short* __restrict__ wbf) {
  int tid = blockIdx.x * 256 + threadIdx.x;
  int k = tid & 511;
  int c = (tid >> 9) & 255;
  int base = tid & ~0x1FFFF;
  int ks = k >> 6;
  int kk = k & 63;
  wbf[base + ks * 16384 + c * 64 + (kk ^ ((c & 7) << 3))] = f2bf(W[tid]);
}

// Layer 0, pipelined: A dbuf (2x32KB) via global_load_lds + counted vmcnt,
// x prefetched to regs one round ahead, B dbuf (2x8KB) written from regs.
// Two barriers/round: vwait sits BEFORE the rendezvous that gates MFMA reads.
__global__ __launch_bounds__(256, 2)
void layer0_kernel(const float* __restrict__ x0,
                   unsigned short* __restrict__ act0,
                   const unsigned short* __restrict__ w0,
                   const float* __restrict__ bias0) {
  __shared__ __align__(16) unsigned char lds[81920];
  const int tid = threadIdx.x;
  const int lane = tid & 63, w = tid >> 6, l15 = lane & 15, l4 = lane >> 4;
  const long n0 = (long)blockIdx.x * 64;

  int cpp[4], fch[4];
#pragma unroll
  for (int p = 0; p < 4; ++p) {
    int idx = p * 256 + tid;
    cpp[p] = idx >> 5;
    fch[p] = idx & 31;
  }

  f32x4 xv[2][4];
#pragma unroll
  for (int rr = 0; rr < 8; ++rr)
    gload16(w0 + rr * 2048 + tid * 8, lds + rr * 4096 + w * 1024);
#pragma unroll
  for (int p = 0; p < 4; ++p)
    xv[0][p] = *(const f32x4*)(x0 + ((long)cpp[p] << 16) + 2 * n0 + 4 * fch[p]);

  f32x4 acc[4][4];
#pragma unroll
  for (int a = 0; a < 4; ++a)
#pragma unroll
    for (int bq = 0; bq < 4; ++bq) acc[a][bq] = (f32x4)0.0f;

#pragma unroll
  for (int r = 0; r < 8; ++r) {
    __builtin_amdgcn_s_barrier();  // protects prefetch target (reads of r-1 done)
    __builtin_amdgcn_sched_barrier(0);
    if (r + 1 < 8) {
      const unsigned short* aw = w0 + (r + 1) * 16384;
      unsigned char* ad = lds + ((r + 1) & 1) * 32768;
#pragma unroll
      for (int rr = 0; rr < 8; ++rr)
        gload16(aw + rr * 2048 + tid * 8, ad + rr * 4096 + w * 1024);
#pragma unroll
      for (int p = 0; p < 4; ++p)
        xv[(r + 1) & 1][p] = *(const f32x4*)(
            x0 + ((long)(32 * (r + 1) + cpp[p]) << 16) + 2 * n0 + 4 * fch[p]);
      __builtin_amdgcn_sched_barrier(0);
      vwait<12>();
    } else {
      vwait<0>();
    }
    __builtin_amdgcn_sched_barrier(0);
    {  // write B(r) from xv[r&1], swizzled rows of 128 B
      unsigned char* bb = lds + 65536 + (r & 1) * 8192;
#pragma unroll
      for (int p = 0; p < 4; ++p) {
        f32x4 v = xv[r & 1][p];
        unsigned int lo = (unsigned)f2bf(v[0]) | ((unsigned)f2bf(v[1]) << 16);
        unsigned int hi = (unsigned)f2bf(v[2]) | ((unsigned)f2bf(v[3]) << 16);
        int colb = 4 * cpp[p];
        int nl = 2 * fch[p];
        *(unsigned int*)(bb + nl * 128 + (colb ^ ((nl & 7) << 4))) = lo;
        nl++;
        *(unsigned int*)(bb + nl * 128 + (colb ^ ((nl & 7) << 4))) = hi;
      }
    }
    asm volatile("s_waitcnt lgkmcnt(0)" ::: "memory");
    __builtin_amdgcn_sched_barrier(0);
    __builtin_amdgcn_s_barrier();  // rendezvous: everyone's A(r)+B(r) staged
    __builtin_amdgcn_sched_barrier(0);
    const unsigned char* Ab = lds + (r & 1) * 32768;
    const unsigned char* Bb = lds + 65536 + (r & 1) * 8192;
#pragma unroll
    for (int k2 = 0; k2 < 2; ++k2) {
      const int acol = k2 * 64 + 16 * l4;
      bhalf8 af[4], bfv[4];
#pragma unroll
      for (int mt = 0; mt < 4; ++mt) {
        int m = 64 * w + 16 * mt + l15;
        af[mt] = *(const bhalf8*)(Ab + m * 128 + (acol ^ ((m & 7) << 4)));
      }
#pragma unroll
      for (int nt = 0; nt < 4; ++nt) {
        int n = 16 * nt + l15;
        bfv[nt] = *(const bhalf8*)(Bb + n * 128 + (acol ^ ((n & 7) << 4)));
      }
#pragma unroll
      for (int mt = 0; mt < 4; ++mt)
#pragma unroll
        for (int nt = 0; nt < 4; ++nt)
          acc[mt][nt] = __builtin_amdgcn_mfma_f32_16x16x32_bf16(
              af[mt], bfv[nt], acc[mt][nt], 0, 0, 0);
    }
  }
  // epilogue: bias+tanh, stage B-layout rows (32 KB) at lds[0..32768)
#pragma unroll
  for (int mt = 0; mt < 4; ++mt) {
    int cb_ = 64 * w + 16 * mt + 4 * l4;
    f32x4 bs4 = *(const f32x4*)(bias0 + cb_);
#pragma unroll
    for (int q = 0; q < 4; ++q) {
      int c = cb_ + q;
#pragma unroll
      for (int nt = 0; nt < 4; ++nt) {
        int n = 16 * nt + l15;
        unsigned short v = f2bf(tanhf(acc[mt][nt][q] + bs4[q]));
        int r2 = n >> 1;
        *(unsigned short*)(lds + r2 * 1024 +
                           ((4 * c + 2 * (n & 1)) ^ ((r2 & 7) << 4))) = v;
      }
    }
  }
  __syncthreads();
#pragma unroll
  for (int p = 0; p < 8; ++p)
    *(u16x8*)(act0 + (long)blockIdx.x * 16384 + p * 2048 + tid * 8) =
        *(const u16x8*)(lds + p * 4096 + tid * 16);
}

// Fused tree: NL layers, block-local. A ring (RING=2: PF1, RING=3: PF2),
// TWO barriers/round: top barrier protects prefetch target, post-vwait
// barrier guarantees all waves' A(r) slices are staged before any MFMA read.
template <int NL, int ROWS_IN, int BN_OUT, int FINAL, int RING>
__global__ __launch_bounds__(256, 1)
void tree_kernel(const unsigned short* __restrict__ actin,
                 unsigned short* __restrict__ actout,
                 float* __restrict__ fout,
                 const unsigned short* __restrict__ wbase,
                 const float* __restrict__ biasbase) {
  constexpr int BIN = ROWS_IN * 1024;
  constexpr int AOFF = BIN;
  __shared__ __align__(16) unsigned char lds[BIN + RING * 32768];
  const int tid = threadIdx.x;
  const int lane = tid & 63, w = tid >> 6, l15 = lane & 15, l4 = lane >> 4;
  const long blk = blockIdx.x;
  constexpr int R = NL * 8;

  {  // prologue: B-in + A(0) [+ A(1) for RING3]
    const unsigned short* src = actin + blk * (ROWS_IN * 512);
#pragma unroll
    for (int rr = 0; rr < BIN / 4096; ++rr)
      gload16(src + rr * 2048 + w * 512 + lane * 8, lds + rr * 4096 + w * 1024);
#pragma unroll
    for (int rr = 0; rr < 8; ++rr)
      gload16(wbase + rr * 2048 + w * 512 + lane * 8,
              lds + AOFF + rr * 4096 + w * 1024);
    if (RING == 3) {
#pragma unroll
      for (int rr = 0; rr < 8; ++rr)
        gload16(wbase + 16384 + rr * 2048 + w * 512 + lane * 8,
                lds + AOFF + 32768 + rr * 4096 + w * 1024);
    }
  }

  f32x4 acc[4][4];
#pragma unroll
  for (int a = 0; a < 4; ++a)
#pragma unroll
    for (int bq = 0; bq < 4; ++bq) acc[a][bq] = (f32x4)0.0f;

#pragma unroll
  for (int j = 0; j < NL; ++j) {
    const int cols = ROWS_IN >> j;
    const int NT = (cols >= 64) ? 4 : (cols >= 32) ? 2 : 1;
    const int in_off = (j & 1) * (BIN / 2);
    const int out_off = (j & 1) ? 0 : (BIN / 2);
#pragma unroll
    for (int ks = 0; ks < 8; ++ks) {
      const int r = j * 8 + ks;
      __builtin_amdgcn_s_barrier();  // all waves done reading prefetch target
      __builtin_amdgcn_sched_barrier(0);
      if (RING == 3) {
        const int rn = r + 2;
        if (rn < R) {
          const unsigned short* aw =
              wbase + (rn >> 3) * 131072 + (rn & 7) * 16384;
          unsigned char* ad = lds + AOFF + (rn % 3) * 32768;
#pragma unroll
          for (int rr2 = 0; rr2 < 8; ++rr2)
            gload16(aw + rr2 * 2048 + w * 512 + lane * 8,
                    ad + rr2 * 4096 + w * 1024);
          __builtin_amdgcn_sched_barrier(0);
          vwait<16>();
        } else if (rn == R) {
          vwait<8>();
        } else {
          vwait<0>();
        }
      } else {
        const int rn = r + 1;
        if (rn < R) {
          const unsigned short* aw =
              wbase + (rn >> 3) * 131072 + (rn & 7) * 16384;
          unsigned char* ad = lds + AOFF + (rn & 1) * 32768;
#pragma unroll
          for (int rr2 = 0; rr2 < 8; ++rr2)
            gload16(aw + rr2 * 2048 + w * 512 + lane * 8,
                    ad + rr2 * 4096 + w * 1024);
          __builtin_amdgcn_sched_barrier(0);
          vwait<8>();
        } else {
          vwait<0>();
        }
      }
      __builtin_amdgcn_sched_barrier(0);
      __builtin_amdgcn_s_barrier();  // rendezvous: A(r) fully staged by all
      __builtin_amdgcn_sched_barrier(0);
      const unsigned char* Ab = lds + AOFF + (r % RING) * 32768;
#pragma unroll
      for (int k2 = 0; k2 < 2; ++k2) {
        const int acol = k2 * 64 + 16 * l4;
        bhalf8 af[4], bfv[4];
#pragma unroll
        for (int mt = 0; mt < 4; ++mt) {
          int m = 64 * w + 16 * mt + l15;
          af[mt] = *(const bhalf8*)(Ab + m * 128 + (acol ^ ((m & 7) << 4)));
        }
        const int bcol = ks * 128 + acol;
#pragma unroll
        for (int nt = 0; nt < 4; ++nt)
          if (nt < NT) {
            int n = 16 * nt + l15;
            bfv[nt] = *(const bhalf8*)(lds + in_off + n * 1024 +
                                       (bcol ^ ((n & 7) << 4)));
          }
#pragma unroll
        for (int mt = 0; mt < 4; ++mt)
#pragma unroll
          for (int nt = 0; nt < 4; ++nt)
            if (nt < NT)
              acc[mt][nt] = __builtin_amdgcn_mfma_f32_16x16x32_bf16(
                  af[mt], bfv[nt], acc[mt][nt], 0, 0, 0);
      }
      if (ks == 7) {
        __builtin_amdgcn_s_barrier();  // all B reads of this layer complete
        __builtin_amdgcn_sched_barrier(0);
        if (FINAL && j == NL - 1) {
          if (l15 == 0) {
#pragma unroll
            for (int mt = 0; mt < 4; ++mt) {
              int cb_ = 64 * w + 16 * mt + 4 * l4;
              f32x4 bs4 = *(const f32x4*)(biasbase + j * 256 + cb_);
#pragma unroll
              for (int q = 0; q < 4; ++q)
                fout[cb_ + q] = tanhf(acc[mt][0][q] + bs4[q]);
            }
          }
        } else if (j == NL - 1 && BN_OUT == 1) {
          long Rg = blk >> 1;
          int par = (int)(blk & 1);
          if (l15 == 0) {
#pragma unroll
            for (int mt = 0; mt < 4; ++mt) {
              int cb_ = 64 * w + 16 * mt + 4 * l4;
              f32x4 bs4 = *(const f32x4*)(biasbase + j * 256 + cb_);
#pragma unroll
              for (int q = 0; q < 4; ++q) {
                int c = cb_ + q;
                unsigned short v = f2bf(tanhf(acc[mt][0][q] + bs4[q]));
                *(unsigned short*)((unsigned char*)actout + Rg * 1024 +
                                   ((4 * c + 2 * par) ^
                                    ((((int)Rg) & 7) << 4))) = v;
              }
            }
          }
        } else {  // write next-layer B-layout into LDS
#pragma unroll
          for (int mt = 0; mt < 4; ++mt) {
            int cb_ = 64 * w + 16 * mt + 4 * l4;
            f32x4 bs4 = *(const f32x4*)(biasbase + j * 256 + cb_);
#pragma unroll
            for (int q = 0; q < 4; ++q) {
              int c = cb_ + q;
#pragma unroll
              for (int nt = 0; nt < 4; ++nt)
                if (nt < NT) {
                  int n = 16 * nt + l15;
                  if (n < cols) {
                    unsigned short v = f2bf(tanhf(acc[mt][nt][q] + bs4[q]));
                    int r2 = n >> 1;
                    *(unsigned short*)(lds + out_off + r2 * 1024 +
                                       ((4 * c + 2 * (n & 1)) ^
                                        ((r2 & 7) << 4))) = v;
                  }
                }
            }
          }
          asm volatile("s_waitcnt lgkmcnt(0)" ::: "memory");
          __builtin_amdgcn_sched_barrier(0);
        }
#pragma unroll
        for (int a = 0; a < 4; ++a)
#pragma unroll
          for (int bq = 0; bq < 4; ++bq) acc[a][bq] = (f32x4)0.0f;
      }
    }
  }
  if (!FINAL && BN_OUT >= 2) {
    __syncthreads();
    constexpr int OUTB = (BN_OUT / 2) * 1024;
    const int src_off = ((NL - 1) & 1) ? 0 : (BIN / 2);
    unsigned short* dst = actout + blk * (BN_OUT / 2) * 512;
#pragma unroll
    for (int p = 0; p < OUTB / 4096; ++p)
      *(u16x8*)(dst + p * 2048 + tid * 8) =
          *(const u16x8*)(lds + src_off + p * 4096 + tid * 16);
  }
}

extern "C" void kernel_launch(void* const* d_in, const int* in_sizes, int n_in,
                              void* d_out, int out_size, void* d_ws, size_t ws_size,
                              hipStream_t stream) {
  (void)in_sizes; (void)n_in; (void)out_size; (void)ws_size;
  const float* x = (const float*)d_in[0];
  const float* W = (const float*)d_in[1];
  const float* b = (const float*)d_in[2];
  float* out = (float*)d_out;
  unsigned short* wbf = (unsigned short*)d_ws;                          // 4 MB
  unsigned short* act0 = (unsigned short*)((char*)d_ws + (4l << 20));   // 16 MB
  unsigned short* act2 = (unsigned short*)((char*)d_ws + (20l << 20));  // 4 MB
  unsigned short* act9 = (unsigned short*)((char*)d_ws + (24l << 20));  // 64 KB

  convert_w_kernel<<<dim3(8192), dim3(256), 0, stream>>>(W, wbf);
  layer0_kernel<<<dim3(512), dim3(256), 0, stream>>>(x, act0, wbf, b);
  tree_kernel<2, 32, 16, 0, 3><<<dim3(512), dim3(256), 0, stream>>>(
      act0, act2, nullptr, wbf + 1 * 131072, b + 1 * 256);  // l1-l2
  tree_kernel<6, 32, 1, 0, 3><<<dim3(128), dim3(256), 0, stream>>>(
      act2, act9, nullptr, wbf + 3 * 131072, b + 3 * 256);  // l3-l8
  tree_kernel<7, 64, 1, 1, 2><<<dim3(1), dim3(256), 0, stream>>>(
      act9, nullptr, out, wbf + 9 * 131072, b + 9 * 256);   // l9-l15
}